// Round 3
// baseline (1117.665 us; speedup 1.0000x reference)
//
#include <hip/hip_runtime.h>
#include <cmath>

typedef unsigned short ushort_t;
typedef __bf16 bf16x8 __attribute__((ext_vector_type(8)));
typedef float  f32x4  __attribute__((ext_vector_type(4)));

#define B_  8
#define S_  2048
#define D_  768
#define MROWS (B_ * S_)       // 16384
#define EPS 1e-5f
#define LDST 40               // LDS row stride in ushorts (32 data + 8 pad, 16B-aligned rows)

__device__ __forceinline__ float b2f(ushort_t u) {
    union { unsigned int i; float f; } v; v.i = ((unsigned int)u) << 16; return v.f;
}
__device__ __forceinline__ ushort_t f2b(float f) {
    union { float f; unsigned int i; } v; v.f = f;
    unsigned int r = v.i + 0x7fffu + ((v.i >> 16) & 1u);
    return (ushort_t)(r >> 16);
}

// fp32 -> bf16 cast, 4 elems/thread
__global__ void cast_f32_bf16(const float* __restrict__ in, ushort_t* __restrict__ outp, long n)
{
    const long i = ((long)blockIdx.x * 256 + threadIdx.x) * 4;
    if (i + 3 < n) {
        const float4 v = *(const float4*)(in + i);
        ushort4 o;
        o.x = f2b(v.x); o.y = f2b(v.y); o.z = f2b(v.z); o.w = f2b(v.w);
        *(ushort4*)(outp + i) = o;
    }
}

// ---------------------------------------------------------------------------
// GEMM, tile 128x128, BK=32, 4 waves, each wave 64x64 via 4x4 16x16x32 MFMAs.
// A is always bf16 row-major [M,K].
// TRANSB=0 (BF32 must be 0): B source = Bt[N][K] bf16 row-major (NT gemm).
// TRANSB=1: B source = W[K][N] row-major, transposed during LDS staging;
//           BF32=1 -> W is fp32 (converted during staging), BF32=0 -> bf16.
// MODE 0: C (bf16) = acc * scale
// MODE 1: C (fp32) = acc + bias[col] + resid[row*N+col]   (bias/resid fp32)
// ---------------------------------------------------------------------------
template<int TRANSB, int MODE, int BF32>
__global__ __launch_bounds__(256)
void gemm_k(const ushort_t* __restrict__ A, const void* __restrict__ Bsrc,
            void* __restrict__ Cv, int M, int N, int Kd, float scale,
            const float* __restrict__ bias, const float* __restrict__ resid)
{
    __shared__ __align__(16) ushort_t As[128 * LDST];
    __shared__ __align__(16) ushort_t Bs[128 * LDST];

    const int tile_n = blockIdx.x * 128;
    const int tile_m = blockIdx.y * 128;
    const int tid  = threadIdx.x;
    const int w    = tid >> 6;
    const int lane = tid & 63;
    const int wr = w >> 1, wc = w & 1;
    const int r16 = lane & 15;
    const int kq  = lane >> 4;

    f32x4 acc[4][4] = {};

    for (int k0 = 0; k0 < Kd; k0 += 32) {
        // --- stage A tile [128 x 32]: 512 16B chunks, 2 per thread ---
        #pragma unroll
        for (int cc = 0; cc < 2; cc++) {
            const int c = tid + cc * 256;
            const int row = c >> 2, col = (c & 3) * 8;
            const uint4 va = *(const uint4*)(A + (long)(tile_m + row) * Kd + k0 + col);
            *(uint4*)&As[row * LDST + col] = va;
        }
        if (TRANSB == 0) {
            const ushort_t* Bt = (const ushort_t*)Bsrc;
            #pragma unroll
            for (int cc = 0; cc < 2; cc++) {
                const int c = tid + cc * 256;
                const int row = c >> 2, col = (c & 3) * 8;
                const uint4 vb = *(const uint4*)(Bt + (long)(tile_n + row) * Kd + k0 + col);
                *(uint4*)&Bs[row * LDST + col] = vb;
            }
        } else {
            // stage W[k0+kr][tile_n+nc] -> Bs[nc][kr] (transpose in LDS)
            #pragma unroll
            for (int i = 0; i < 16; i++) {
                const int lin = i * 256 + tid;       // 0..4095
                const int kr = lin >> 7, nc = lin & 127;
                ushort_t bv;
                if (BF32) bv = f2b(((const float*)Bsrc)[(long)(k0 + kr) * N + tile_n + nc]);
                else      bv = ((const ushort_t*)Bsrc)[(long)(k0 + kr) * N + tile_n + nc];
                Bs[nc * LDST + kr] = bv;
            }
        }
        __syncthreads();

        bf16x8 af[4], bg[4];
        #pragma unroll
        for (int i = 0; i < 4; i++) {
            af[i] = *reinterpret_cast<const bf16x8*>(&As[(wr * 64 + i * 16 + r16) * LDST + kq * 8]);
            bg[i] = *reinterpret_cast<const bf16x8*>(&Bs[(wc * 64 + i * 16 + r16) * LDST + kq * 8]);
        }
        #pragma unroll
        for (int mi = 0; mi < 4; mi++)
            #pragma unroll
            for (int ni = 0; ni < 4; ni++)
                acc[mi][ni] = __builtin_amdgcn_mfma_f32_16x16x32_bf16(af[mi], bg[ni], acc[mi][ni], 0, 0, 0);
        __syncthreads();
    }

    // C/D layout: col = lane&15, row = (lane>>4)*4 + reg  [m89-verified]
    if (MODE == 0) {
        ushort_t* C = (ushort_t*)Cv;
        #pragma unroll
        for (int mi = 0; mi < 4; mi++)
            #pragma unroll
            for (int ni = 0; ni < 4; ni++)
                #pragma unroll
                for (int r = 0; r < 4; r++) {
                    const int row = tile_m + wr * 64 + mi * 16 + kq * 4 + r;
                    const int col = tile_n + wc * 64 + ni * 16 + r16;
                    C[(long)row * N + col] = f2b(acc[mi][ni][r] * scale);
                }
    } else {
        float* C = (float*)Cv;
        #pragma unroll
        for (int mi = 0; mi < 4; mi++)
            #pragma unroll
            for (int ni = 0; ni < 4; ni++)
                #pragma unroll
                for (int r = 0; r < 4; r++) {
                    const int row = tile_m + wr * 64 + mi * 16 + kq * 4 + r;
                    const int col = tile_n + wc * 64 + ni * 16 + r16;
                    C[(long)row * N + col] =
                        acc[mi][ni][r] + bias[col] + resid[(long)row * N + col];
                }
    }
}

// ---------------------------------------------------------------------------
// softmax over rows of 2048 bf16, in place. one block (256 thr) per row
// ---------------------------------------------------------------------------
__global__ void softmax_rows(ushort_t* __restrict__ p)
{
    __shared__ float sm[4], ss_[4];
    ushort_t* pr = p + (long)blockIdx.x * 2048;
    const int tid = threadIdx.x;
    const int w = tid >> 6;
    float v[8];
    float mx = -3.0e38f;
    #pragma unroll
    for (int i = 0; i < 8; i++) { v[i] = b2f(pr[tid + i * 256]); mx = fmaxf(mx, v[i]); }
    #pragma unroll
    for (int off = 32; off; off >>= 1) mx = fmaxf(mx, __shfl_xor(mx, off));
    if ((tid & 63) == 0) sm[w] = mx;
    __syncthreads();
    mx = fmaxf(fmaxf(sm[0], sm[1]), fmaxf(sm[2], sm[3]));
    float s = 0.f;
    #pragma unroll
    for (int i = 0; i < 8; i++) { v[i] = __expf(v[i] - mx); s += v[i]; }
    #pragma unroll
    for (int off = 32; off; off >>= 1) s += __shfl_xor(s, off);
    if ((tid & 63) == 0) ss_[w] = s;
    __syncthreads();
    s = ss_[0] + ss_[1] + ss_[2] + ss_[3];
    const float inv = 1.f / s;
    #pragma unroll
    for (int i = 0; i < 8; i++) pr[tid + i * 256] = f2b(v[i] * inv);
}

// ---------------------------------------------------------------------------
// double layernorm per fp32 row of 768, IN PLACE. one block (256 thr) per row
// ---------------------------------------------------------------------------
__global__ void ln_fused(float* __restrict__ x,
                         const float* __restrict__ w1, const float* __restrict__ b1,
                         const float* __restrict__ w2, const float* __restrict__ b2)
{
    __shared__ float r1s[4], r1q[4], r2s[4], r2q[4];
    const long row = blockIdx.x;
    const int tid = threadIdx.x;
    const int w = tid >> 6;
    float* xr = x + row * 768;
    float v[3], s = 0.f, q = 0.f;
    #pragma unroll
    for (int i = 0; i < 3; i++) { const float t = xr[tid + i * 256]; v[i] = t; s += t; q += t * t; }
    #pragma unroll
    for (int off = 32; off; off >>= 1) { s += __shfl_xor(s, off); q += __shfl_xor(q, off); }
    if ((tid & 63) == 0) { r1s[w] = s; r1q[w] = q; }
    __syncthreads();
    s = r1s[0] + r1s[1] + r1s[2] + r1s[3];
    q = r1q[0] + r1q[1] + r1q[2] + r1q[3];
    float mu = s * (1.f / 768.f);
    float ri = rsqrtf(q * (1.f / 768.f) - mu * mu + EPS);
    float y[3];
    s = 0.f; q = 0.f;
    #pragma unroll
    for (int i = 0; i < 3; i++) {
        const int d = tid + i * 256;
        const float t = (v[i] - mu) * ri * w1[d] + b1[d];
        y[i] = t; s += t; q += t * t;
    }
    #pragma unroll
    for (int off = 32; off; off >>= 1) { s += __shfl_xor(s, off); q += __shfl_xor(q, off); }
    if ((tid & 63) == 0) { r2s[w] = s; r2q[w] = q; }
    __syncthreads();
    s = r2s[0] + r2s[1] + r2s[2] + r2s[3];
    q = r2q[0] + r2q[1] + r2q[2] + r2q[3];
    mu = s * (1.f / 768.f);
    ri = rsqrtf(q * (1.f / 768.f) - mu * mu + EPS);
    #pragma unroll
    for (int i = 0; i < 3; i++) {
        const int d = tid + i * 256;
        xr[d] = (y[i] - mu) * ri * w2[d] + b2[d];
    }
}

// pooled[b][d] += sum over 128 rows of x[b, sp*128.., d]   (x fp32)
__global__ void pool_reduce(const float* __restrict__ x, float* __restrict__ pooled)
{
    const int d  = blockIdx.x * 256 + threadIdx.x;   // 0..767
    const int b  = blockIdx.z;
    const int sp = blockIdx.y;
    const float* base = x + ((long)b * 2048 + sp * 128) * 768 + d;
    float s = 0.f;
    #pragma unroll 8
    for (int i = 0; i < 128; i++) s += base[(long)i * 768];
    atomicAdd(&pooled[b * 768 + d], s);
}

__global__ void logits_kernel(const float* __restrict__ pooled, const float* __restrict__ Wc,
                              const float* __restrict__ bc, float* __restrict__ out)
{
    const int t = threadIdx.x;
    if (t < 80) {
        const int b = t / 10, o = t % 10;
        const float* pb = pooled + b * 768;
        float s = bc[o];
        for (int d = 0; d < 768; d++) s += pb[d] * (1.f / 2048.f) * Wc[d * 10 + o];
        out[b * 10 + o] = s;
    }
}

extern "C" void kernel_launch(void* const* d_in, const int* in_sizes, int n_in,
                              void* d_out, int out_size, void* d_ws, size_t ws_size,
                              hipStream_t stream)
{
    (void)in_sizes; (void)n_in; (void)out_size; (void)ws_size;
    const float* src  = (const float*)d_in[0];
    const float* Wq   = (const float*)d_in[1];
    const float* Wk   = (const float*)d_in[2];
    const float* Wv   = (const float*)d_in[3];
    const float* Wo   = (const float*)d_in[4];
    const float* bo   = (const float*)d_in[5];
    const float* ln1w = (const float*)d_in[6];
    const float* ln1b = (const float*)d_in[7];
    const float* ln2w = (const float*)d_in[8];
    const float* ln2b = (const float*)d_in[9];
    const float* Wc   = (const float*)d_in[10];
    const float* bc   = (const float*)d_in[11];
    float* out = (float*)d_out;

    char* ws = (char*)d_ws;
    size_t off = 0;
    auto alloc = [&](size_t bytes) { void* p = ws + off; off += (bytes + 255) & ~(size_t)255; return p; };

    // ws total: 4 x 25.17 MB + 3 KB ~= 100.7 MB
    ushort_t* srcb  = (ushort_t*)alloc((size_t)MROWS * 768 * 2);
    ushort_t* Qb    = (ushort_t*)alloc((size_t)MROWS * 768 * 2);
    ushort_t* Kb    = (ushort_t*)alloc((size_t)MROWS * 768 * 2);
    ushort_t* Vb    = (ushort_t*)alloc((size_t)MROWS * 768 * 2);
    float*    pooled= (float*)   alloc(B_ * 768 * 4);
    ushort_t* probs = srcb;             // srcb dead after QKV projections (8.39 MB < 25.17 MB)
    ushort_t* attn  = Qb;               // Q[bz] dead once scores[bz] done
    float*    xpre  = out + 80;         // x written straight into d_out, LN'd in place

    const dim3 blk(256);
    const float qscale = 1.0f / sqrtf(768.0f);
    const long bstride = (long)2048 * 768;

    // src -> bf16
    cast_f32_bf16<<<MROWS * 768 / 1024, blk, 0, stream>>>(src, srcb, (long)MROWS * 768);

    // QKV projections: [16384,768] @ W[768,768]  (W fp32, transposed+cast during staging)
    gemm_k<1, 0, 1><<<dim3(6, 128), blk, 0, stream>>>(srcb, Wq, Qb, MROWS, 768, 768, qscale, nullptr, nullptr);
    gemm_k<1, 0, 1><<<dim3(6, 128), blk, 0, stream>>>(srcb, Wk, Kb, MROWS, 768, 768, 1.0f, nullptr, nullptr);
    gemm_k<1, 0, 1><<<dim3(6, 128), blk, 0, stream>>>(srcb, Wv, Vb, MROWS, 768, 768, 1.0f, nullptr, nullptr);

    for (int bz = 0; bz < B_; bz++) {
        // scores = Qs @ K^T : [2048,768] x [2048,768]^T -> [2048,2048] bf16
        gemm_k<0, 0, 0><<<dim3(16, 16), blk, 0, stream>>>(Qb + bz * bstride, Kb + bz * bstride, probs,
                                                          2048, 2048, 768, 1.0f, nullptr, nullptr);
        softmax_rows<<<2048, blk, 0, stream>>>(probs);
        // attn = P @ V : [2048,2048] x V[2048,768] -> [2048,768] bf16
        gemm_k<1, 0, 0><<<dim3(6, 16), blk, 0, stream>>>(probs, Vb + bz * bstride, attn + bz * bstride,
                                                         2048, 768, 2048, 1.0f, nullptr, nullptr);
    }

    // x_pre = attn @ Wo + bo + src  -> fp32 straight into out+80
    gemm_k<1, 1, 1><<<dim3(6, 128), blk, 0, stream>>>(attn, Wo, xpre, MROWS, 768, 768, 1.0f, bo, src);

    // double layernorm in place (fp32)
    ln_fused<<<MROWS, blk, 0, stream>>>(xpre, ln1w, ln1b, ln2w, ln2b);

    // pooled mean over S, then logits
    hipMemsetAsync(pooled, 0, B_ * 768 * 4, stream);
    pool_reduce<<<dim3(3, 16, B_), blk, 0, stream>>>(xpre, pooled);
    logits_kernel<<<1, 128, 0, stream>>>(pooled, Wc, bc, out);
}

// Round 4
// 547.087 us; speedup vs baseline: 2.0429x; 2.0429x over previous
//
#include <hip/hip_runtime.h>
#include <cmath>

typedef unsigned short ushort_t;
typedef __bf16 bf16x8 __attribute__((ext_vector_type(8)));
typedef float  f32x4  __attribute__((ext_vector_type(4)));

#define B_  8
#define S_  2048
#define D_  768
#define MROWS (B_ * S_)       // 16384
#define EPS 1e-5f
#define LDST 40               // padded stride for fallback gemm only

__device__ __forceinline__ float b2f(ushort_t u) {
    union { unsigned int i; float f; } v; v.i = ((unsigned int)u) << 16; return v.f;
}
__device__ __forceinline__ ushort_t f2b(float f) {
    union { float f; unsigned int i; } v; v.f = f;
    unsigned int r = v.i + 0x7fffu + ((v.i >> 16) & 1u);
    return (ushort_t)(r >> 16);
}

// async 16B global->LDS; LDS dest = wave-uniform base + lane*16
__device__ __forceinline__ void gload16(const ushort_t* g, ushort_t* l) {
    __builtin_amdgcn_global_load_lds((__attribute__((address_space(1))) void*)g,
                                     (__attribute__((address_space(3))) void*)l,
                                     16, 0, 0);
}

// fp32 -> bf16 cast, 4 elems/thread
__global__ void cast_f32_bf16(const float* __restrict__ in, ushort_t* __restrict__ outp, long n)
{
    const long i = ((long)blockIdx.x * 256 + threadIdx.x) * 4;
    if (i + 3 < n) {
        const float4 v = *(const float4*)(in + i);
        ushort4 o;
        o.x = f2b(v.x); o.y = f2b(v.y); o.z = f2b(v.z); o.w = f2b(v.w);
        *(ushort4*)(outp + i) = o;
    }
}

// ---------------------------------------------------------------------------
// transpose (+optional fp32->bf16 cast): dst[C][R] = cvt(src[R][C]), z-batched
// ---------------------------------------------------------------------------
template<int F32IN>
__global__ void transpose_any(const void* __restrict__ srcv, ushort_t* __restrict__ dst,
                              int R, int C, long sb, long db)
{
    __shared__ ushort_t tile[64 * 65];
    dst += (long)blockIdx.z * db;
    const int r0 = blockIdx.y * 64, c0 = blockIdx.x * 64;
    const int t = threadIdx.x;
    const int tr = t >> 6, tc = t & 63;
    #pragma unroll
    for (int i = 0; i < 16; i++) {
        const int r = i * 4 + tr;
        ushort_t v;
        if (F32IN) v = f2b(((const float*)srcv + (long)blockIdx.z * sb)[(long)(r0 + r) * C + (c0 + tc)]);
        else       v = ((const ushort_t*)srcv + (long)blockIdx.z * sb)[(long)(r0 + r) * C + (c0 + tc)];
        tile[r * 65 + tc] = v;
    }
    __syncthreads();
    #pragma unroll
    for (int i = 0; i < 16; i++) {
        const int r = i * 4 + tr;
        dst[(long)(c0 + r) * R + (r0 + tc)] = tile[tc * 65 + r];
    }
}

// ---------------------------------------------------------------------------
// Fast NT GEMM (m97 structure): C[M,N] = A[M,K] * Bt[N,K]^T, bf16 in, fp32 acc
// global_load_lds width-16 staging, XOR-swizzled LDS (32-ushort rows, no pad)
// MODE 0: C (bf16) = acc * scale
// MODE 1: C (fp32) = acc + bias[col] + resid[row*N+col]     (z must be 1)
// tile 128x128, BK=32, 4 waves, each wave 64x64 via 4x4 16x16x32 MFMAs
// ---------------------------------------------------------------------------
template<int MODE>
__global__ __launch_bounds__(256)
void gemm_nt(const ushort_t* __restrict__ A, const ushort_t* __restrict__ Bt,
             void* __restrict__ Cv, int M, int N, int Kd,
             long batchA, long batchB, long batchC, float scale,
             const float* __restrict__ bias, const float* __restrict__ resid)
{
    __shared__ __align__(16) ushort_t As[128 * 32];
    __shared__ __align__(16) ushort_t Bs[128 * 32];

    const int bz = blockIdx.z;
    A  += (long)bz * batchA;
    Bt += (long)bz * batchB;

    const int tile_n = blockIdx.x * 128;
    const int tile_m = blockIdx.y * 128;
    const int tid  = threadIdx.x;
    const int w    = tid >> 6;
    const int lane = tid & 63;
    const int wr = w >> 1, wc = w & 1;
    const int r16 = lane & 15;
    const int kq  = lane >> 4;

    // staging: lane -> (row = lane>>2 within 16-row group, chunk = lane&3)
    const int srow   = lane >> 2;
    const int schunk = lane & 3;
    const int arow0 = w * 32 + srow;
    const int arow1 = arow0 + 16;
    // XOR swizzle: LDS chunk c holds global chunk c ^ ((row>>1)&3)
    const int g0 = (schunk ^ ((arow0 >> 1) & 3)) * 8;
    const int g1 = (schunk ^ ((arow1 >> 1) & 3)) * 8;

    const ushort_t* Ar0 = A  + (long)(tile_m + arow0) * Kd + g0;
    const ushort_t* Ar1 = A  + (long)(tile_m + arow1) * Kd + g1;
    const ushort_t* Br0 = Bt + (long)(tile_n + arow0) * Kd + g0;
    const ushort_t* Br1 = Bt + (long)(tile_n + arow1) * Kd + g1;

    ushort_t* lA0 = &As[(w * 32     ) * 32];
    ushort_t* lA1 = &As[(w * 32 + 16) * 32];
    ushort_t* lB0 = &Bs[(w * 32     ) * 32];
    ushort_t* lB1 = &Bs[(w * 32 + 16) * 32];

    f32x4 acc[4][4] = {};

    for (int k0 = 0; k0 < Kd; k0 += 32) {
        gload16(Ar0 + k0, lA0);
        gload16(Ar1 + k0, lA1);
        gload16(Br0 + k0, lB0);
        gload16(Br1 + k0, lB1);
        __syncthreads();

        bf16x8 af[4], bg[4];
        #pragma unroll
        for (int i = 0; i < 4; i++) {
            const int ra = wr * 64 + i * 16 + r16;
            af[i] = *reinterpret_cast<const bf16x8*>(&As[ra * 32 + ((kq ^ ((ra >> 1) & 3)) * 8)]);
            const int rb = wc * 64 + i * 16 + r16;
            bg[i] = *reinterpret_cast<const bf16x8*>(&Bs[rb * 32 + ((kq ^ ((rb >> 1) & 3)) * 8)]);
        }
        #pragma unroll
        for (int mi = 0; mi < 4; mi++)
            #pragma unroll
            for (int ni = 0; ni < 4; ni++)
                acc[mi][ni] = __builtin_amdgcn_mfma_f32_16x16x32_bf16(af[mi], bg[ni], acc[mi][ni], 0, 0, 0);
        __syncthreads();
    }

    // C/D layout: col = lane&15, row = (lane>>4)*4 + reg  [m89-verified]
    if (MODE == 0) {
        ushort_t* C = (ushort_t*)Cv + (long)bz * batchC;
        #pragma unroll
        for (int mi = 0; mi < 4; mi++)
            #pragma unroll
            for (int ni = 0; ni < 4; ni++)
                #pragma unroll
                for (int r = 0; r < 4; r++) {
                    const int row = tile_m + wr * 64 + mi * 16 + kq * 4 + r;
                    const int col = tile_n + wc * 64 + ni * 16 + r16;
                    C[(long)row * N + col] = f2b(acc[mi][ni][r] * scale);
                }
    } else {
        float* C = (float*)Cv;
        #pragma unroll
        for (int mi = 0; mi < 4; mi++)
            #pragma unroll
            for (int ni = 0; ni < 4; ni++)
                #pragma unroll
                for (int r = 0; r < 4; r++) {
                    const int row = tile_m + wr * 64 + mi * 16 + kq * 4 + r;
                    const int col = tile_n + wc * 64 + ni * 16 + r16;
                    C[(long)row * N + col] =
                        acc[mi][ni][r] + bias[col] + resid[(long)row * N + col];
                }
    }
}

// ---------------------------------------------------------------------------
// Fallback GEMM (round-3 proven, padded LDS, register staging) — used only
// if ws_size is too small for the fast paths.
// ---------------------------------------------------------------------------
template<int TRANSB, int MODE, int BF32>
__global__ __launch_bounds__(256)
void gemm_s(const ushort_t* __restrict__ A, const void* __restrict__ Bsrc,
            void* __restrict__ Cv, int M, int N, int Kd, float scale,
            const float* __restrict__ bias, const float* __restrict__ resid)
{
    __shared__ __align__(16) ushort_t As[128 * LDST];
    __shared__ __align__(16) ushort_t Bs[128 * LDST];
    const int tile_n = blockIdx.x * 128;
    const int tile_m = blockIdx.y * 128;
    const int tid  = threadIdx.x;
    const int w    = tid >> 6;
    const int lane = tid & 63;
    const int wr = w >> 1, wc = w & 1;
    const int r16 = lane & 15;
    const int kq  = lane >> 4;
    f32x4 acc[4][4] = {};
    for (int k0 = 0; k0 < Kd; k0 += 32) {
        #pragma unroll
        for (int cc = 0; cc < 2; cc++) {
            const int c = tid + cc * 256;
            const int row = c >> 2, col = (c & 3) * 8;
            *(uint4*)&As[row * LDST + col] = *(const uint4*)(A + (long)(tile_m + row) * Kd + k0 + col);
        }
        if (TRANSB == 0) {
            const ushort_t* Bt = (const ushort_t*)Bsrc;
            #pragma unroll
            for (int cc = 0; cc < 2; cc++) {
                const int c = tid + cc * 256;
                const int row = c >> 2, col = (c & 3) * 8;
                *(uint4*)&Bs[row * LDST + col] = *(const uint4*)(Bt + (long)(tile_n + row) * Kd + k0 + col);
            }
        } else {
            #pragma unroll
            for (int i = 0; i < 16; i++) {
                const int lin = i * 256 + tid;
                const int kr = lin >> 7, nc = lin & 127;
                ushort_t bv;
                if (BF32) bv = f2b(((const float*)Bsrc)[(long)(k0 + kr) * N + tile_n + nc]);
                else      bv = ((const ushort_t*)Bsrc)[(long)(k0 + kr) * N + tile_n + nc];
                Bs[nc * LDST + kr] = bv;
            }
        }
        __syncthreads();
        bf16x8 af[4], bg[4];
        #pragma unroll
        for (int i = 0; i < 4; i++) {
            af[i] = *reinterpret_cast<const bf16x8*>(&As[(wr * 64 + i * 16 + r16) * LDST + kq * 8]);
            bg[i] = *reinterpret_cast<const bf16x8*>(&Bs[(wc * 64 + i * 16 + r16) * LDST + kq * 8]);
        }
        #pragma unroll
        for (int mi = 0; mi < 4; mi++)
            #pragma unroll
            for (int ni = 0; ni < 4; ni++)
                acc[mi][ni] = __builtin_amdgcn_mfma_f32_16x16x32_bf16(af[mi], bg[ni], acc[mi][ni], 0, 0, 0);
        __syncthreads();
    }
    if (MODE == 0) {
        ushort_t* C = (ushort_t*)Cv;
        #pragma unroll
        for (int mi = 0; mi < 4; mi++)
            #pragma unroll
            for (int ni = 0; ni < 4; ni++)
                #pragma unroll
                for (int r = 0; r < 4; r++) {
                    const int row = tile_m + wr * 64 + mi * 16 + kq * 4 + r;
                    const int col = tile_n + wc * 64 + ni * 16 + r16;
                    C[(long)row * N + col] = f2b(acc[mi][ni][r] * scale);
                }
    } else {
        float* C = (float*)Cv;
        #pragma unroll
        for (int mi = 0; mi < 4; mi++)
            #pragma unroll
            for (int ni = 0; ni < 4; ni++)
                #pragma unroll
                for (int r = 0; r < 4; r++) {
                    const int row = tile_m + wr * 64 + mi * 16 + kq * 4 + r;
                    const int col = tile_n + wc * 64 + ni * 16 + r16;
                    C[(long)row * N + col] =
                        acc[mi][ni][r] + bias[col] + resid[(long)row * N + col];
                }
    }
}

// ---------------------------------------------------------------------------
// softmax over rows of 2048 bf16, in place, vectorized 16B/lane
// ---------------------------------------------------------------------------
__global__ void softmax_rows(ushort_t* __restrict__ p)
{
    __shared__ float sm[4], ss_[4];
    ushort_t* pr = p + (long)blockIdx.x * 2048;
    const int tid = threadIdx.x;
    const int w = tid >> 6;
    const uint4 raw = *(const uint4*)(pr + tid * 8);
    float v[8];
    v[0] = b2f((ushort_t)(raw.x & 0xffff)); v[1] = b2f((ushort_t)(raw.x >> 16));
    v[2] = b2f((ushort_t)(raw.y & 0xffff)); v[3] = b2f((ushort_t)(raw.y >> 16));
    v[4] = b2f((ushort_t)(raw.z & 0xffff)); v[5] = b2f((ushort_t)(raw.z >> 16));
    v[6] = b2f((ushort_t)(raw.w & 0xffff)); v[7] = b2f((ushort_t)(raw.w >> 16));
    float mx = -3.0e38f;
    #pragma unroll
    for (int i = 0; i < 8; i++) mx = fmaxf(mx, v[i]);
    #pragma unroll
    for (int off = 32; off; off >>= 1) mx = fmaxf(mx, __shfl_xor(mx, off));
    if ((tid & 63) == 0) sm[w] = mx;
    __syncthreads();
    mx = fmaxf(fmaxf(sm[0], sm[1]), fmaxf(sm[2], sm[3]));
    float s = 0.f;
    #pragma unroll
    for (int i = 0; i < 8; i++) { v[i] = __expf(v[i] - mx); s += v[i]; }
    #pragma unroll
    for (int off = 32; off; off >>= 1) s += __shfl_xor(s, off);
    if ((tid & 63) == 0) ss_[w] = s;
    __syncthreads();
    s = ss_[0] + ss_[1] + ss_[2] + ss_[3];
    const float inv = 1.f / s;
    uint4 o;
    o.x = f2b(v[0] * inv) | ((unsigned)f2b(v[1] * inv) << 16);
    o.y = f2b(v[2] * inv) | ((unsigned)f2b(v[3] * inv) << 16);
    o.z = f2b(v[4] * inv) | ((unsigned)f2b(v[5] * inv) << 16);
    o.w = f2b(v[6] * inv) | ((unsigned)f2b(v[7] * inv) << 16);
    *(uint4*)(pr + tid * 8) = o;
}

// ---------------------------------------------------------------------------
// double layernorm per fp32 row of 768, IN PLACE. one block (256 thr) per row
// ---------------------------------------------------------------------------
__global__ void ln_fused(float* __restrict__ x,
                         const float* __restrict__ w1, const float* __restrict__ b1,
                         const float* __restrict__ w2, const float* __restrict__ b2)
{
    __shared__ float r1s[4], r1q[4], r2s[4], r2q[4];
    const long row = blockIdx.x;
    const int tid = threadIdx.x;
    const int w = tid >> 6;
    float* xr = x + row * 768;
    float v[3], s = 0.f, q = 0.f;
    #pragma unroll
    for (int i = 0; i < 3; i++) { const float t = xr[tid + i * 256]; v[i] = t; s += t; q += t * t; }
    #pragma unroll
    for (int off = 32; off; off >>= 1) { s += __shfl_xor(s, off); q += __shfl_xor(q, off); }
    if ((tid & 63) == 0) { r1s[w] = s; r1q[w] = q; }
    __syncthreads();
    s = r1s[0] + r1s[1] + r1s[2] + r1s[3];
    q = r1q[0] + r1q[1] + r1q[2] + r1q[3];
    float mu = s * (1.f / 768.f);
    float ri = rsqrtf(q * (1.f / 768.f) - mu * mu + EPS);
    float y[3];
    s = 0.f; q = 0.f;
    #pragma unroll
    for (int i = 0; i < 3; i++) {
        const int d = tid + i * 256;
        const float t = (v[i] - mu) * ri * w1[d] + b1[d];
        y[i] = t; s += t; q += t * t;
    }
    #pragma unroll
    for (int off = 32; off; off >>= 1) { s += __shfl_xor(s, off); q += __shfl_xor(q, off); }
    if ((tid & 63) == 0) { r2s[w] = s; r2q[w] = q; }
    __syncthreads();
    s = r2s[0] + r2s[1] + r2s[2] + r2s[3];
    q = r2q[0] + r2q[1] + r2q[2] + r2q[3];
    mu = s * (1.f / 768.f);
    ri = rsqrtf(q * (1.f / 768.f) - mu * mu + EPS);
    #pragma unroll
    for (int i = 0; i < 3; i++) {
        const int d = tid + i * 256;
        xr[d] = (y[i] - mu) * ri * w2[d] + b2[d];
    }
}

__global__ void pool_reduce(const float* __restrict__ x, float* __restrict__ pooled)
{
    const int d  = blockIdx.x * 256 + threadIdx.x;
    const int b  = blockIdx.z;
    const int sp = blockIdx.y;
    const float* base = x + ((long)b * 2048 + sp * 128) * 768 + d;
    float s = 0.f;
    #pragma unroll 8
    for (int i = 0; i < 128; i++) s += base[(long)i * 768];
    atomicAdd(&pooled[b * 768 + d], s);
}

__global__ void logits_kernel(const float* __restrict__ pooled, const float* __restrict__ Wc,
                              const float* __restrict__ bc, float* __restrict__ out)
{
    const int t = threadIdx.x;
    if (t < 80) {
        const int b = t / 10, o = t % 10;
        const float* pb = pooled + b * 768;
        float s = bc[o];
        for (int d = 0; d < 768; d++) s += pb[d] * (1.f / 2048.f) * Wc[d * 10 + o];
        out[b * 10 + o] = s;
    }
}

extern "C" void kernel_launch(void* const* d_in, const int* in_sizes, int n_in,
                              void* d_out, int out_size, void* d_ws, size_t ws_size,
                              hipStream_t stream)
{
    (void)in_sizes; (void)n_in; (void)out_size;
    const float* src  = (const float*)d_in[0];
    const float* Wq   = (const float*)d_in[1];
    const float* Wk   = (const float*)d_in[2];
    const float* Wv   = (const float*)d_in[3];
    const float* Wo   = (const float*)d_in[4];
    const float* bo   = (const float*)d_in[5];
    const float* ln1w = (const float*)d_in[6];
    const float* ln1b = (const float*)d_in[7];
    const float* ln2w = (const float*)d_in[8];
    const float* ln2b = (const float*)d_in[9];
    const float* Wc   = (const float*)d_in[10];
    const float* bc   = (const float*)d_in[11];
    float* out = (float*)d_out;

    const dim3 blk(256);
    const float qscale = 1.0f / sqrtf(768.0f);
    const long bs = (long)2048 * 768;

    const size_t WT    = (size_t)768 * 768 * 2;          // 1,179,648 (256-mult)
    const size_t BUF   = (size_t)MROWS * 768 * 2;        // 25,165,824
    const size_t POOLB = 24576;
    const size_t PROBS8 = (size_t)8 * 2048 * 2048 * 2;   // 67,108,864
    const size_t needB = 4 * WT + 5 * BUF + POOLB;       // ~130.6 MB
    const size_t needA = needB + PROBS8;                 // ~197.7 MB

    char* ws = (char*)d_ws;
    size_t off = 0;
    auto alloc = [&](size_t bytes) { void* p = ws + off; off += (bytes + 255) & ~(size_t)255; return p; };

    if (ws_size >= needB) {
        // ---------------- fast paths ----------------
        ushort_t* Wtq  = (ushort_t*)alloc(WT);
        ushort_t* Wtk  = (ushort_t*)alloc(WT);
        ushort_t* Wtv  = (ushort_t*)alloc(WT);
        ushort_t* Wto  = (ushort_t*)alloc(WT);
        ushort_t* srcb = (ushort_t*)alloc(BUF);
        ushort_t* Qb   = (ushort_t*)alloc(BUF);
        ushort_t* Kb   = (ushort_t*)alloc(BUF);
        ushort_t* Vb   = (ushort_t*)alloc(BUF);
        ushort_t* Vt   = (ushort_t*)alloc(BUF);
        float*  pooled = (float*)  alloc(POOLB);
        const bool batched = (ws_size >= needA);
        ushort_t* probs = batched ? (ushort_t*)alloc(PROBS8) : srcb;  // srcb dead after QKV
        ushort_t* attn  = Vb;                                         // Vb dead after transpose
        float*    xpre  = out + 80;

        cast_f32_bf16<<<MROWS * 768 / 1024, blk, 0, stream>>>(src, srcb, (long)MROWS * 768);
        transpose_any<1><<<dim3(12, 12, 1), blk, 0, stream>>>(Wq, Wtq, 768, 768, 0, 0);
        transpose_any<1><<<dim3(12, 12, 1), blk, 0, stream>>>(Wk, Wtk, 768, 768, 0, 0);
        transpose_any<1><<<dim3(12, 12, 1), blk, 0, stream>>>(Wv, Wtv, 768, 768, 0, 0);
        transpose_any<1><<<dim3(12, 12, 1), blk, 0, stream>>>(Wo, Wto, 768, 768, 0, 0);

        gemm_nt<0><<<dim3(6, 128, 1), blk, 0, stream>>>(srcb, Wtq, Qb, MROWS, 768, 768, 0, 0, 0, qscale, nullptr, nullptr);
        gemm_nt<0><<<dim3(6, 128, 1), blk, 0, stream>>>(srcb, Wtk, Kb, MROWS, 768, 768, 0, 0, 0, 1.0f, nullptr, nullptr);
        gemm_nt<0><<<dim3(6, 128, 1), blk, 0, stream>>>(srcb, Wtv, Vb, MROWS, 768, 768, 0, 0, 0, 1.0f, nullptr, nullptr);

        // V^T per batch: [2048,768] -> [768,2048]
        transpose_any<0><<<dim3(12, 32, B_), blk, 0, stream>>>(Vb, Vt, 2048, 768, bs, bs);

        if (batched) {
            gemm_nt<0><<<dim3(16, 16, B_), blk, 0, stream>>>(Qb, Kb, probs, 2048, 2048, 768,
                                                             bs, bs, (long)2048 * 2048, 1.0f, nullptr, nullptr);
            softmax_rows<<<B_ * 2048, blk, 0, stream>>>(probs);
            gemm_nt<0><<<dim3(6, 16, B_), blk, 0, stream>>>(probs, Vt, attn, 2048, 768, 2048,
                                                            (long)2048 * 2048, bs, bs, 1.0f, nullptr, nullptr);
        } else {
            for (int bz = 0; bz < B_; bz += 2) {   // z=2 chunks; probs (16.8 MB) fits srcb (25.2 MB)
                gemm_nt<0><<<dim3(16, 16, 2), blk, 0, stream>>>(Qb + bz * bs, Kb + bz * bs, probs,
                                                                2048, 2048, 768, bs, bs, (long)2048 * 2048,
                                                                1.0f, nullptr, nullptr);
                softmax_rows<<<2 * 2048, blk, 0, stream>>>(probs);
                gemm_nt<0><<<dim3(6, 16, 2), blk, 0, stream>>>(probs, Vt, attn + bz * bs, 2048, 768, 2048,
                                                               (long)2048 * 2048, bs, bs, 1.0f, nullptr, nullptr);
            }
        }

        gemm_nt<1><<<dim3(6, 128, 1), blk, 0, stream>>>(attn, Wto, xpre, MROWS, 768, 768, 0, 0, 0, 1.0f, bo, src);
        ln_fused<<<MROWS, blk, 0, stream>>>(xpre, ln1w, ln1b, ln2w, ln2b);
        hipMemsetAsync(pooled, 0, B_ * 768 * 4, stream);
        pool_reduce<<<dim3(3, 16, B_), blk, 0, stream>>>(xpre, pooled);
        logits_kernel<<<1, 128, 0, stream>>>(pooled, Wc, bc, out);
    } else {
        // ---------------- round-3 proven fallback (~100.7 MB) ----------------
        ushort_t* srcb = (ushort_t*)alloc(BUF);
        ushort_t* Qb   = (ushort_t*)alloc(BUF);
        ushort_t* Kb   = (ushort_t*)alloc(BUF);
        ushort_t* Vb   = (ushort_t*)alloc(BUF);
        float*  pooled = (float*)  alloc(POOLB);
        ushort_t* probs = srcb;
        ushort_t* attn  = Qb;
        float*    xpre  = out + 80;

        cast_f32_bf16<<<MROWS * 768 / 1024, blk, 0, stream>>>(src, srcb, (long)MROWS * 768);
        gemm_s<1, 0, 1><<<dim3(6, 128), blk, 0, stream>>>(srcb, Wq, Qb, MROWS, 768, 768, qscale, nullptr, nullptr);
        gemm_s<1, 0, 1><<<dim3(6, 128), blk, 0, stream>>>(srcb, Wk, Kb, MROWS, 768, 768, 1.0f, nullptr, nullptr);
        gemm_s<1, 0, 1><<<dim3(6, 128), blk, 0, stream>>>(srcb, Wv, Vb, MROWS, 768, 768, 1.0f, nullptr, nullptr);
        for (int bz = 0; bz < B_; bz++) {
            gemm_s<0, 0, 0><<<dim3(16, 16), blk, 0, stream>>>(Qb + bz * bs, Kb + bz * bs, probs,
                                                              2048, 2048, 768, 1.0f, nullptr, nullptr);
            softmax_rows<<<2048, blk, 0, stream>>>(probs);
            gemm_s<1, 0, 0><<<dim3(6, 16), blk, 0, stream>>>(probs, Vb + bz * bs, attn + bz * bs,
                                                             2048, 768, 2048, 1.0f, nullptr, nullptr);
        }
        gemm_s<1, 1, 1><<<dim3(6, 128), blk, 0, stream>>>(attn, Wo, xpre, MROWS, 768, 768, 1.0f, bo, src);
        ln_fused<<<MROWS, blk, 0, stream>>>(xpre, ln1w, ln1b, ln2w, ln2b);
        hipMemsetAsync(pooled, 0, B_ * 768 * 4, stream);
        pool_reduce<<<dim3(3, 16, B_), blk, 0, stream>>>(xpre, pooled);
        logits_kernel<<<1, 128, 0, stream>>>(pooled, Wc, bc, out);
    }
}

// Round 5
// 521.055 us; speedup vs baseline: 2.1450x; 1.0500x over previous
//
#include <hip/hip_runtime.h>
#include <cmath>

typedef unsigned short ushort_t;
typedef __bf16 bf16x8 __attribute__((ext_vector_type(8)));
typedef float  f32x4  __attribute__((ext_vector_type(4)));

#define B_  8
#define S_  2048
#define D_  768
#define MROWS (B_ * S_)       // 16384
#define EPS 1e-5f
#define LDST 40               // padded stride for fallback gemm only

__device__ __forceinline__ float b2f(ushort_t u) {
    union { unsigned int i; float f; } v; v.i = ((unsigned int)u) << 16; return v.f;
}
__device__ __forceinline__ ushort_t f2b(float f) {
    union { float f; unsigned int i; } v; v.f = f;
    unsigned int r = v.i + 0x7fffu + ((v.i >> 16) & 1u);
    return (ushort_t)(r >> 16);
}

// async 16B global->LDS; LDS dest = wave-uniform base + lane*16
__device__ __forceinline__ void gload16(const ushort_t* g, ushort_t* l) {
    __builtin_amdgcn_global_load_lds((__attribute__((address_space(1))) void*)g,
                                     (__attribute__((address_space(3))) void*)l,
                                     16, 0, 0);
}

// fp32 -> bf16 cast, 4 elems/thread
__global__ void cast_f32_bf16(const float* __restrict__ in, ushort_t* __restrict__ outp, long n)
{
    const long i = ((long)blockIdx.x * 256 + threadIdx.x) * 4;
    if (i + 3 < n) {
        const float4 v = *(const float4*)(in + i);
        ushort4 o;
        o.x = f2b(v.x); o.y = f2b(v.y); o.z = f2b(v.z); o.w = f2b(v.w);
        *(ushort4*)(outp + i) = o;
    }
}

// ---------------------------------------------------------------------------
// transpose (+optional fp32->bf16 cast): dst[C][R] = cvt(src[R][C]), z-batched
// ---------------------------------------------------------------------------
template<int F32IN>
__global__ void transpose_any(const void* __restrict__ srcv, ushort_t* __restrict__ dst,
                              int R, int C, long sb, long db)
{
    __shared__ ushort_t tile[64 * 65];
    dst += (long)blockIdx.z * db;
    const int r0 = blockIdx.y * 64, c0 = blockIdx.x * 64;
    const int t = threadIdx.x;
    const int tr = t >> 6, tc = t & 63;
    #pragma unroll
    for (int i = 0; i < 16; i++) {
        const int r = i * 4 + tr;
        ushort_t v;
        if (F32IN) v = f2b(((const float*)srcv + (long)blockIdx.z * sb)[(long)(r0 + r) * C + (c0 + tc)]);
        else       v = ((const ushort_t*)srcv + (long)blockIdx.z * sb)[(long)(r0 + r) * C + (c0 + tc)];
        tile[r * 65 + tc] = v;
    }
    __syncthreads();
    #pragma unroll
    for (int i = 0; i < 16; i++) {
        const int r = i * 4 + tr;
        dst[(long)(c0 + r) * R + (r0 + tc)] = tile[tc * 65 + r];
    }
}

// ---------------------------------------------------------------------------
// Fast NT GEMM (m97 structure): C[M,N] = A[M,K] * Bt[N,K]^T, bf16 in, fp32 acc
// global_load_lds width-16 staging, XOR-swizzled LDS (32-ushort rows, no pad)
// XCD-aware block swizzle: hardware assigns linear%8 -> XCD; remap so each XCD
// owns a contiguous run of M-tiles x all N-tiles (per-XCD L2 working set <~4MB)
// MODE 0: C (bf16) = acc * scale
// MODE 1: C (fp32) = acc + bias[col] + resid[row*N+col]     (z must be 1)
// ---------------------------------------------------------------------------
template<int MODE>
__global__ __launch_bounds__(256)
void gemm_nt(const ushort_t* __restrict__ A, const ushort_t* __restrict__ Bt,
             void* __restrict__ Cv, int M, int N, int Kd,
             long batchA, long batchB, long batchC, float scale,
             const float* __restrict__ bias, const float* __restrict__ resid)
{
    __shared__ __align__(16) ushort_t As[128 * 32];
    __shared__ __align__(16) ushort_t Bs[128 * 32];

    const int bz = blockIdx.z;
    A  += (long)bz * batchA;
    Bt += (long)bz * batchB;

    // ---- XCD-aware swizzle ----
    const int nxt  = gridDim.x;
    const int nblk = nxt * gridDim.y;
    int lin = blockIdx.y * nxt + blockIdx.x;
    if ((nblk & 7) == 0) {
        const int per = nblk >> 3;
        lin = (lin & 7) * per + (lin >> 3);
    }
    const int tile_n = (lin % nxt) * 128;
    const int tile_m = (lin / nxt) * 128;

    const int tid  = threadIdx.x;
    const int w    = tid >> 6;
    const int lane = tid & 63;
    const int wr = w >> 1, wc = w & 1;
    const int r16 = lane & 15;
    const int kq  = lane >> 4;

    // staging: lane -> (row = lane>>2 within 16-row group, chunk = lane&3)
    const int srow   = lane >> 2;
    const int schunk = lane & 3;
    const int arow0 = w * 32 + srow;
    const int arow1 = arow0 + 16;
    // XOR swizzle: LDS chunk c holds global chunk c ^ ((row>>1)&3)
    const int g0 = (schunk ^ ((arow0 >> 1) & 3)) * 8;
    const int g1 = (schunk ^ ((arow1 >> 1) & 3)) * 8;

    const ushort_t* Ar0 = A  + (long)(tile_m + arow0) * Kd + g0;
    const ushort_t* Ar1 = A  + (long)(tile_m + arow1) * Kd + g1;
    const ushort_t* Br0 = Bt + (long)(tile_n + arow0) * Kd + g0;
    const ushort_t* Br1 = Bt + (long)(tile_n + arow1) * Kd + g1;

    ushort_t* lA0 = &As[(w * 32     ) * 32];
    ushort_t* lA1 = &As[(w * 32 + 16) * 32];
    ushort_t* lB0 = &Bs[(w * 32     ) * 32];
    ushort_t* lB1 = &Bs[(w * 32 + 16) * 32];

    f32x4 acc[4][4] = {};

    for (int k0 = 0; k0 < Kd; k0 += 32) {
        gload16(Ar0 + k0, lA0);
        gload16(Ar1 + k0, lA1);
        gload16(Br0 + k0, lB0);
        gload16(Br1 + k0, lB1);
        __syncthreads();

        bf16x8 af[4], bg[4];
        #pragma unroll
        for (int i = 0; i < 4; i++) {
            const int ra = wr * 64 + i * 16 + r16;
            af[i] = *reinterpret_cast<const bf16x8*>(&As[ra * 32 + ((kq ^ ((ra >> 1) & 3)) * 8)]);
            const int rb = wc * 64 + i * 16 + r16;
            bg[i] = *reinterpret_cast<const bf16x8*>(&Bs[rb * 32 + ((kq ^ ((rb >> 1) & 3)) * 8)]);
        }
        #pragma unroll
        for (int mi = 0; mi < 4; mi++)
            #pragma unroll
            for (int ni = 0; ni < 4; ni++)
                acc[mi][ni] = __builtin_amdgcn_mfma_f32_16x16x32_bf16(af[mi], bg[ni], acc[mi][ni], 0, 0, 0);
        __syncthreads();
    }

    // C/D layout: col = lane&15, row = (lane>>4)*4 + reg  [m89-verified]
    if (MODE == 0) {
        ushort_t* C = (ushort_t*)Cv + (long)bz * batchC;
        #pragma unroll
        for (int mi = 0; mi < 4; mi++)
            #pragma unroll
            for (int ni = 0; ni < 4; ni++)
                #pragma unroll
                for (int r = 0; r < 4; r++) {
                    const int row = tile_m + wr * 64 + mi * 16 + kq * 4 + r;
                    const int col = tile_n + wc * 64 + ni * 16 + r16;
                    C[(long)row * N + col] = f2b(acc[mi][ni][r] * scale);
                }
    } else {
        float* C = (float*)Cv;
        #pragma unroll
        for (int mi = 0; mi < 4; mi++)
            #pragma unroll
            for (int ni = 0; ni < 4; ni++)
                #pragma unroll
                for (int r = 0; r < 4; r++) {
                    const int row = tile_m + wr * 64 + mi * 16 + kq * 4 + r;
                    const int col = tile_n + wc * 64 + ni * 16 + r16;
                    C[(long)row * N + col] =
                        acc[mi][ni][r] + bias[col] + resid[(long)row * N + col];
                }
    }
}

// ---------------------------------------------------------------------------
// Fallback GEMM (round-3 proven, padded LDS, register staging) — only if ws
// is too small for the fast paths.
// ---------------------------------------------------------------------------
template<int TRANSB, int MODE, int BF32>
__global__ __launch_bounds__(256)
void gemm_s(const ushort_t* __restrict__ A, const void* __restrict__ Bsrc,
            void* __restrict__ Cv, int M, int N, int Kd, float scale,
            const float* __restrict__ bias, const float* __restrict__ resid)
{
    __shared__ __align__(16) ushort_t As[128 * LDST];
    __shared__ __align__(16) ushort_t Bs[128 * LDST];
    const int tile_n = blockIdx.x * 128;
    const int tile_m = blockIdx.y * 128;
    const int tid  = threadIdx.x;
    const int w    = tid >> 6;
    const int lane = tid & 63;
    const int wr = w >> 1, wc = w & 1;
    const int r16 = lane & 15;
    const int kq  = lane >> 4;
    f32x4 acc[4][4] = {};
    for (int k0 = 0; k0 < Kd; k0 += 32) {
        #pragma unroll
        for (int cc = 0; cc < 2; cc++) {
            const int c = tid + cc * 256;
            const int row = c >> 2, col = (c & 3) * 8;
            *(uint4*)&As[row * LDST + col] = *(const uint4*)(A + (long)(tile_m + row) * Kd + k0 + col);
        }
        if (TRANSB == 0) {
            const ushort_t* Bt = (const ushort_t*)Bsrc;
            #pragma unroll
            for (int cc = 0; cc < 2; cc++) {
                const int c = tid + cc * 256;
                const int row = c >> 2, col = (c & 3) * 8;
                *(uint4*)&Bs[row * LDST + col] = *(const uint4*)(Bt + (long)(tile_n + row) * Kd + k0 + col);
            }
        } else {
            #pragma unroll
            for (int i = 0; i < 16; i++) {
                const int lin = i * 256 + tid;
                const int kr = lin >> 7, nc = lin & 127;
                ushort_t bv;
                if (BF32) bv = f2b(((const float*)Bsrc)[(long)(k0 + kr) * N + tile_n + nc]);
                else      bv = ((const ushort_t*)Bsrc)[(long)(k0 + kr) * N + tile_n + nc];
                Bs[nc * LDST + kr] = bv;
            }
        }
        __syncthreads();
        bf16x8 af[4], bg[4];
        #pragma unroll
        for (int i = 0; i < 4; i++) {
            af[i] = *reinterpret_cast<const bf16x8*>(&As[(wr * 64 + i * 16 + r16) * LDST + kq * 8]);
            bg[i] = *reinterpret_cast<const bf16x8*>(&Bs[(wc * 64 + i * 16 + r16) * LDST + kq * 8]);
        }
        #pragma unroll
        for (int mi = 0; mi < 4; mi++)
            #pragma unroll
            for (int ni = 0; ni < 4; ni++)
                acc[mi][ni] = __builtin_amdgcn_mfma_f32_16x16x32_bf16(af[mi], bg[ni], acc[mi][ni], 0, 0, 0);
        __syncthreads();
    }
    if (MODE == 0) {
        ushort_t* C = (ushort_t*)Cv;
        #pragma unroll
        for (int mi = 0; mi < 4; mi++)
            #pragma unroll
            for (int ni = 0; ni < 4; ni++)
                #pragma unroll
                for (int r = 0; r < 4; r++) {
                    const int row = tile_m + wr * 64 + mi * 16 + kq * 4 + r;
                    const int col = tile_n + wc * 64 + ni * 16 + r16;
                    C[(long)row * N + col] = f2b(acc[mi][ni][r] * scale);
                }
    } else {
        float* C = (float*)Cv;
        #pragma unroll
        for (int mi = 0; mi < 4; mi++)
            #pragma unroll
            for (int ni = 0; ni < 4; ni++)
                #pragma unroll
                for (int r = 0; r < 4; r++) {
                    const int row = tile_m + wr * 64 + mi * 16 + kq * 4 + r;
                    const int col = tile_n + wc * 64 + ni * 16 + r16;
                    C[(long)row * N + col] =
                        acc[mi][ni][r] + bias[col] + resid[(long)row * N + col];
                }
    }
}

// ---------------------------------------------------------------------------
// softmax over rows of 2048 bf16, in place, vectorized 16B/lane
// ---------------------------------------------------------------------------
__global__ void softmax_rows(ushort_t* __restrict__ p)
{
    __shared__ float sm[4], ss_[4];
    ushort_t* pr = p + (long)blockIdx.x * 2048;
    const int tid = threadIdx.x;
    const int w = tid >> 6;
    const uint4 raw = *(const uint4*)(pr + tid * 8);
    float v[8];
    v[0] = b2f((ushort_t)(raw.x & 0xffff)); v[1] = b2f((ushort_t)(raw.x >> 16));
    v[2] = b2f((ushort_t)(raw.y & 0xffff)); v[3] = b2f((ushort_t)(raw.y >> 16));
    v[4] = b2f((ushort_t)(raw.z & 0xffff)); v[5] = b2f((ushort_t)(raw.z >> 16));
    v[6] = b2f((ushort_t)(raw.w & 0xffff)); v[7] = b2f((ushort_t)(raw.w >> 16));
    float mx = -3.0e38f;
    #pragma unroll
    for (int i = 0; i < 8; i++) mx = fmaxf(mx, v[i]);
    #pragma unroll
    for (int off = 32; off; off >>= 1) mx = fmaxf(mx, __shfl_xor(mx, off));
    if ((tid & 63) == 0) sm[w] = mx;
    __syncthreads();
    mx = fmaxf(fmaxf(sm[0], sm[1]), fmaxf(sm[2], sm[3]));
    float s = 0.f;
    #pragma unroll
    for (int i = 0; i < 8; i++) { v[i] = __expf(v[i] - mx); s += v[i]; }
    #pragma unroll
    for (int off = 32; off; off >>= 1) s += __shfl_xor(s, off);
    if ((tid & 63) == 0) ss_[w] = s;
    __syncthreads();
    s = ss_[0] + ss_[1] + ss_[2] + ss_[3];
    const float inv = 1.f / s;
    uint4 o;
    o.x = f2b(v[0] * inv) | ((unsigned)f2b(v[1] * inv) << 16);
    o.y = f2b(v[2] * inv) | ((unsigned)f2b(v[3] * inv) << 16);
    o.z = f2b(v[4] * inv) | ((unsigned)f2b(v[5] * inv) << 16);
    o.w = f2b(v[6] * inv) | ((unsigned)f2b(v[7] * inv) << 16);
    *(uint4*)(pr + tid * 8) = o;
}

// ---------------------------------------------------------------------------
// double layernorm per fp32 row of 768, IN PLACE. one block (256 thr) per row
// ---------------------------------------------------------------------------
__global__ void ln_fused(float* __restrict__ x,
                         const float* __restrict__ w1, const float* __restrict__ b1,
                         const float* __restrict__ w2, const float* __restrict__ b2)
{
    __shared__ float r1s[4], r1q[4], r2s[4], r2q[4];
    const long row = blockIdx.x;
    const int tid = threadIdx.x;
    const int w = tid >> 6;
    float* xr = x + row * 768;
    float v[3], s = 0.f, q = 0.f;
    #pragma unroll
    for (int i = 0; i < 3; i++) { const float t = xr[tid + i * 256]; v[i] = t; s += t; q += t * t; }
    #pragma unroll
    for (int off = 32; off; off >>= 1) { s += __shfl_xor(s, off); q += __shfl_xor(q, off); }
    if ((tid & 63) == 0) { r1s[w] = s; r1q[w] = q; }
    __syncthreads();
    s = r1s[0] + r1s[1] + r1s[2] + r1s[3];
    q = r1q[0] + r1q[1] + r1q[2] + r1q[3];
    float mu = s * (1.f / 768.f);
    float ri = rsqrtf(q * (1.f / 768.f) - mu * mu + EPS);
    float y[3];
    s = 0.f; q = 0.f;
    #pragma unroll
    for (int i = 0; i < 3; i++) {
        const int d = tid + i * 256;
        const float t = (v[i] - mu) * ri * w1[d] + b1[d];
        y[i] = t; s += t; q += t * t;
    }
    #pragma unroll
    for (int off = 32; off; off >>= 1) { s += __shfl_xor(s, off); q += __shfl_xor(q, off); }
    if ((tid & 63) == 0) { r2s[w] = s; r2q[w] = q; }
    __syncthreads();
    s = r2s[0] + r2s[1] + r2s[2] + r2s[3];
    q = r2q[0] + r2q[1] + r2q[2] + r2q[3];
    mu = s * (1.f / 768.f);
    ri = rsqrtf(q * (1.f / 768.f) - mu * mu + EPS);
    #pragma unroll
    for (int i = 0; i < 3; i++) {
        const int d = tid + i * 256;
        xr[d] = (y[i] - mu) * ri * w2[d] + b2[d];
    }
}

__global__ void pool_reduce(const float* __restrict__ x, float* __restrict__ pooled)
{
    const int d  = blockIdx.x * 256 + threadIdx.x;
    const int b  = blockIdx.z;
    const int sp = blockIdx.y;
    const float* base = x + ((long)b * 2048 + sp * 128) * 768 + d;
    float s = 0.f;
    #pragma unroll 8
    for (int i = 0; i < 128; i++) s += base[(long)i * 768];
    atomicAdd(&pooled[b * 768 + d], s);
}

__global__ void logits_kernel(const float* __restrict__ pooled, const float* __restrict__ Wc,
                              const float* __restrict__ bc, float* __restrict__ out)
{
    const int t = threadIdx.x;
    if (t < 80) {
        const int b = t / 10, o = t % 10;
        const float* pb = pooled + b * 768;
        float s = bc[o];
        for (int d = 0; d < 768; d++) s += pb[d] * (1.f / 2048.f) * Wc[d * 10 + o];
        out[b * 10 + o] = s;
    }
}

extern "C" void kernel_launch(void* const* d_in, const int* in_sizes, int n_in,
                              void* d_out, int out_size, void* d_ws, size_t ws_size,
                              hipStream_t stream)
{
    (void)in_sizes; (void)n_in; (void)out_size;
    const float* src  = (const float*)d_in[0];
    const float* Wq   = (const float*)d_in[1];
    const float* Wk   = (const float*)d_in[2];
    const float* Wv   = (const float*)d_in[3];
    const float* Wo   = (const float*)d_in[4];
    const float* bo   = (const float*)d_in[5];
    const float* ln1w = (const float*)d_in[6];
    const float* ln1b = (const float*)d_in[7];
    const float* ln2w = (const float*)d_in[8];
    const float* ln2b = (const float*)d_in[9];
    const float* Wc   = (const float*)d_in[10];
    const float* bc   = (const float*)d_in[11];
    float* out = (float*)d_out;

    const dim3 blk(256);
    const float qscale = 1.0f / sqrtf(768.0f);
    const long bs = (long)2048 * 768;

    const size_t WT    = (size_t)768 * 768 * 2;
    const size_t BUF   = (size_t)MROWS * 768 * 2;
    const size_t POOLB = 24576;
    const size_t PROBS8 = (size_t)8 * 2048 * 2048 * 2;
    const size_t needB = 4 * WT + 5 * BUF + POOLB;       // ~130.6 MB
    const size_t needA = needB + PROBS8;                 // ~197.7 MB

    char* ws = (char*)d_ws;
    size_t off = 0;
    auto alloc = [&](size_t bytes) { void* p = ws + off; off += (bytes + 255) & ~(size_t)255; return p; };

    if (ws_size >= needB) {
        ushort_t* Wtq  = (ushort_t*)alloc(WT);
        ushort_t* Wtk  = (ushort_t*)alloc(WT);
        ushort_t* Wtv  = (ushort_t*)alloc(WT);
        ushort_t* Wto  = (ushort_t*)alloc(WT);
        ushort_t* srcb = (ushort_t*)alloc(BUF);
        ushort_t* Qb   = (ushort_t*)alloc(BUF);
        ushort_t* Kb   = (ushort_t*)alloc(BUF);
        ushort_t* Vb   = (ushort_t*)alloc(BUF);
        ushort_t* Vt   = (ushort_t*)alloc(BUF);
        float*  pooled = (float*)  alloc(POOLB);
        const bool batched = (ws_size >= needA);
        ushort_t* probs = batched ? (ushort_t*)alloc(PROBS8) : srcb;  // srcb dead after QKV
        ushort_t* attn  = Vb;                                         // Vb dead after transpose
        float*    xpre  = out + 80;

        cast_f32_bf16<<<MROWS * 768 / 1024, blk, 0, stream>>>(src, srcb, (long)MROWS * 768);
        transpose_any<1><<<dim3(12, 12, 1), blk, 0, stream>>>(Wq, Wtq, 768, 768, 0, 0);
        transpose_any<1><<<dim3(12, 12, 1), blk, 0, stream>>>(Wk, Wtk, 768, 768, 0, 0);
        transpose_any<1><<<dim3(12, 12, 1), blk, 0, stream>>>(Wv, Wtv, 768, 768, 0, 0);
        transpose_any<1><<<dim3(12, 12, 1), blk, 0, stream>>>(Wo, Wto, 768, 768, 0, 0);

        gemm_nt<0><<<dim3(6, 128, 1), blk, 0, stream>>>(srcb, Wtq, Qb, MROWS, 768, 768, 0, 0, 0, qscale, nullptr, nullptr);
        gemm_nt<0><<<dim3(6, 128, 1), blk, 0, stream>>>(srcb, Wtk, Kb, MROWS, 768, 768, 0, 0, 0, 1.0f, nullptr, nullptr);
        gemm_nt<0><<<dim3(6, 128, 1), blk, 0, stream>>>(srcb, Wtv, Vb, MROWS, 768, 768, 0, 0, 0, 1.0f, nullptr, nullptr);

        transpose_any<0><<<dim3(12, 32, B_), blk, 0, stream>>>(Vb, Vt, 2048, 768, bs, bs);

        if (batched) {
            gemm_nt<0><<<dim3(16, 16, B_), blk, 0, stream>>>(Qb, Kb, probs, 2048, 2048, 768,
                                                             bs, bs, (long)2048 * 2048, 1.0f, nullptr, nullptr);
            softmax_rows<<<B_ * 2048, blk, 0, stream>>>(probs);
            gemm_nt<0><<<dim3(6, 16, B_), blk, 0, stream>>>(probs, Vt, attn, 2048, 768, 2048,
                                                            (long)2048 * 2048, bs, bs, 1.0f, nullptr, nullptr);
        } else {
            for (int bz = 0; bz < B_; bz += 2) {
                gemm_nt<0><<<dim3(16, 16, 2), blk, 0, stream>>>(Qb + bz * bs, Kb + bz * bs, probs,
                                                                2048, 2048, 768, bs, bs, (long)2048 * 2048,
                                                                1.0f, nullptr, nullptr);
                softmax_rows<<<2 * 2048, blk, 0, stream>>>(probs);
                gemm_nt<0><<<dim3(6, 16, 2), blk, 0, stream>>>(probs, Vt, attn + bz * bs, 2048, 768, 2048,
                                                               (long)2048 * 2048, bs, bs, 1.0f, nullptr, nullptr);
            }
        }

        gemm_nt<1><<<dim3(6, 128, 1), blk, 0, stream>>>(attn, Wto, xpre, MROWS, 768, 768, 0, 0, 0, 1.0f, bo, src);
        ln_fused<<<MROWS, blk, 0, stream>>>(xpre, ln1w, ln1b, ln2w, ln2b);
        hipMemsetAsync(pooled, 0, B_ * 768 * 4, stream);
        pool_reduce<<<dim3(3, 16, B_), blk, 0, stream>>>(xpre, pooled);
        logits_kernel<<<1, 128, 0, stream>>>(pooled, Wc, bc, out);
    } else {
        ushort_t* srcb = (ushort_t*)alloc(BUF);
        ushort_t* Qb   = (ushort_t*)alloc(BUF);
        ushort_t* Kb   = (ushort_t*)alloc(BUF);
        ushort_t* Vb   = (ushort_t*)alloc(BUF);
        float*  pooled = (float*)  alloc(POOLB);
        ushort_t* probs = srcb;
        ushort_t* attn  = Qb;
        float*    xpre  = out + 80;

        cast_f32_bf16<<<MROWS * 768 / 1024, blk, 0, stream>>>(src, srcb, (long)MROWS * 768);
        gemm_s<1, 0, 1><<<dim3(6, 128), blk, 0, stream>>>(srcb, Wq, Qb, MROWS, 768, 768, qscale, nullptr, nullptr);
        gemm_s<1, 0, 1><<<dim3(6, 128), blk, 0, stream>>>(srcb, Wk, Kb, MROWS, 768, 768, 1.0f, nullptr, nullptr);
        gemm_s<1, 0, 1><<<dim3(6, 128), blk, 0, stream>>>(srcb, Wv, Vb, MROWS, 768, 768, 1.0f, nullptr, nullptr);
        for (int bz = 0; bz < B_; bz++) {
            gemm_s<0, 0, 0><<<dim3(16, 16), blk, 0, stream>>>(Qb + bz * bs, Kb + bz * bs, probs,
                                                              2048, 2048, 768, 1.0f, nullptr, nullptr);
            softmax_rows<<<2048, blk, 0, stream>>>(probs);
            gemm_s<1, 0, 0><<<dim3(6, 16), blk, 0, stream>>>(probs, Vb + bz * bs, attn + bz * bs,
                                                             2048, 768, 2048, 1.0f, nullptr, nullptr);
        }
        gemm_s<1, 1, 1><<<dim3(6, 128), blk, 0, stream>>>(attn, Wo, xpre, MROWS, 768, 768, 1.0f, bo, src);
        ln_fused<<<MROWS, blk, 0, stream>>>(xpre, ln1w, ln1b, ln2w, ln2b);
        hipMemsetAsync(pooled, 0, B_ * 768 * 4, stream);
        pool_reduce<<<dim3(3, 16, B_), blk, 0, stream>>>(xpre, pooled);
        logits_kernel<<<1, 128, 0, stream>>>(pooled, Wc, bc, out);
    }
}

// Round 7
// 474.386 us; speedup vs baseline: 2.3560x; 1.0984x over previous
//
#include <hip/hip_runtime.h>
#include <cmath>

typedef unsigned short ushort_t;
typedef __bf16 bf16x8 __attribute__((ext_vector_type(8)));
typedef float  f32x4  __attribute__((ext_vector_type(4)));

#define B_  8
#define S_  2048
#define D_  768
#define MROWS (B_ * S_)       // 16384
#define EPS 1e-5f
#define LDST 40               // padded stride for fallback gemm only

__device__ __forceinline__ float b2f(ushort_t u) {
    union { unsigned int i; float f; } v; v.i = ((unsigned int)u) << 16; return v.f;
}
__device__ __forceinline__ ushort_t f2b(float f) {
    union { float f; unsigned int i; } v; v.f = f;
    unsigned int r = v.i + 0x7fffu + ((v.i >> 16) & 1u);
    return (ushort_t)(r >> 16);
}

// async 16B global->LDS; LDS dest = wave-uniform base + lane*16
__device__ __forceinline__ void gload16(const ushort_t* g, ushort_t* l) {
    __builtin_amdgcn_global_load_lds((__attribute__((address_space(1))) void*)g,
                                     (__attribute__((address_space(3))) void*)l,
                                     16, 0, 0);
}

// fp32 -> bf16 cast, 4 elems/thread
__global__ void cast_f32_bf16(const float* __restrict__ in, ushort_t* __restrict__ outp, long n)
{
    const long i = ((long)blockIdx.x * 256 + threadIdx.x) * 4;
    if (i + 3 < n) {
        const float4 v = *(const float4*)(in + i);
        ushort4 o;
        o.x = f2b(v.x); o.y = f2b(v.y); o.z = f2b(v.z); o.w = f2b(v.w);
        *(ushort4*)(outp + i) = o;
    }
}

// ---------------------------------------------------------------------------
// transpose (+optional fp32->bf16 cast): dst[C][R] = cvt(src[R][C]), z-batched
// ---------------------------------------------------------------------------
template<int F32IN>
__global__ void transpose_any(const void* __restrict__ srcv, ushort_t* __restrict__ dst,
                              int R, int C, long sb, long db)
{
    __shared__ ushort_t tile[64 * 65];
    dst += (long)blockIdx.z * db;
    const int r0 = blockIdx.y * 64, c0 = blockIdx.x * 64;
    const int t = threadIdx.x;
    const int tr = t >> 6, tc = t & 63;
    #pragma unroll
    for (int i = 0; i < 16; i++) {
        const int r = i * 4 + tr;
        ushort_t v;
        if (F32IN) v = f2b(((const float*)srcv + (long)blockIdx.z * sb)[(long)(r0 + r) * C + (c0 + tc)]);
        else       v = ((const ushort_t*)srcv + (long)blockIdx.z * sb)[(long)(r0 + r) * C + (c0 + tc)];
        tile[r * 65 + tc] = v;
    }
    __syncthreads();
    #pragma unroll
    for (int i = 0; i < 16; i++) {
        const int r = i * 4 + tr;
        dst[(long)(c0 + r) * R + (r0 + tc)] = tile[tc * 65 + r];
    }
}

// ---------------------------------------------------------------------------
// Fast NT GEMM (m97 structure): C[M,N] = A[M,K] * Bt[N,K]^T, bf16 in, fp32 acc
// global_load_lds width-16 staging, XOR-swizzled LDS, XCD-aware block swizzle.
// MODE 0: C (bf16) = acc * scale
// MODE 1: C (fp32) = acc + bias[col] + resid[row*N+col]     (z must be 1)
// MODE 2: C (bf16) = acc / rowsum[bz*2048 + row]            (PV, normalize)
// MODE 3: C (bf16) = exp(acc*scale); atomicAdd row sums     (scores, fused softmax)
// MODE 4: QKV split: Cv=Qb base; sect=tile_n/768 routes to Q/K/V; qscale on Q
// ---------------------------------------------------------------------------
template<int MODE>
__global__ __launch_bounds__(256)
void gemm_nt(const ushort_t* __restrict__ A, const ushort_t* __restrict__ Bt,
             void* __restrict__ Cv, int M, int N, int Kd,
             long batchA, long batchB, long batchC, float scale,
             const float* __restrict__ bias, const float* __restrict__ resid,
             float* __restrict__ rowsum)
{
    __shared__ __align__(16) ushort_t As[128 * 32];
    __shared__ __align__(16) ushort_t Bs[128 * 32];

    const int bz = blockIdx.z;
    A  += (long)bz * batchA;
    Bt += (long)bz * batchB;

    // ---- XCD-aware swizzle (hardware: linear%8 -> XCD) ----
    const int nxt  = gridDim.x;
    const int nblk = nxt * gridDim.y;
    int lin = blockIdx.y * nxt + blockIdx.x;
    if ((nblk & 7) == 0) {
        const int per = nblk >> 3;
        lin = (lin & 7) * per + (lin >> 3);
    }
    const int tile_n = (lin % nxt) * 128;
    const int tile_m = (lin / nxt) * 128;

    const int tid  = threadIdx.x;
    const int w    = tid >> 6;
    const int lane = tid & 63;
    const int wr = w >> 1, wc = w & 1;
    const int r16 = lane & 15;
    const int kq  = lane >> 4;

    const int srow   = lane >> 2;
    const int schunk = lane & 3;
    const int arow0 = w * 32 + srow;
    const int arow1 = arow0 + 16;
    const int g0 = (schunk ^ ((arow0 >> 1) & 3)) * 8;
    const int g1 = (schunk ^ ((arow1 >> 1) & 3)) * 8;

    const ushort_t* Ar0 = A  + (long)(tile_m + arow0) * Kd + g0;
    const ushort_t* Ar1 = A  + (long)(tile_m + arow1) * Kd + g1;
    const ushort_t* Br0 = Bt + (long)(tile_n + arow0) * Kd + g0;
    const ushort_t* Br1 = Bt + (long)(tile_n + arow1) * Kd + g1;

    ushort_t* lA0 = &As[(w * 32     ) * 32];
    ushort_t* lA1 = &As[(w * 32 + 16) * 32];
    ushort_t* lB0 = &Bs[(w * 32     ) * 32];
    ushort_t* lB1 = &Bs[(w * 32 + 16) * 32];

    f32x4 acc[4][4] = {};

    for (int k0 = 0; k0 < Kd; k0 += 32) {
        gload16(Ar0 + k0, lA0);
        gload16(Ar1 + k0, lA1);
        gload16(Br0 + k0, lB0);
        gload16(Br1 + k0, lB1);
        __syncthreads();

        bf16x8 af[4], bg[4];
        #pragma unroll
        for (int i = 0; i < 4; i++) {
            const int ra = wr * 64 + i * 16 + r16;
            af[i] = *reinterpret_cast<const bf16x8*>(&As[ra * 32 + ((kq ^ ((ra >> 1) & 3)) * 8)]);
            const int rb = wc * 64 + i * 16 + r16;
            bg[i] = *reinterpret_cast<const bf16x8*>(&Bs[rb * 32 + ((kq ^ ((rb >> 1) & 3)) * 8)]);
        }
        #pragma unroll
        for (int mi = 0; mi < 4; mi++)
            #pragma unroll
            for (int ni = 0; ni < 4; ni++)
                acc[mi][ni] = __builtin_amdgcn_mfma_f32_16x16x32_bf16(af[mi], bg[ni], acc[mi][ni], 0, 0, 0);
        __syncthreads();
    }

    // C/D layout: col = lane&15, row = (lane>>4)*4 + reg  [m89-verified]
    if (MODE == 0) {
        ushort_t* C = (ushort_t*)Cv + (long)bz * batchC;
        #pragma unroll
        for (int mi = 0; mi < 4; mi++)
            #pragma unroll
            for (int ni = 0; ni < 4; ni++)
                #pragma unroll
                for (int r = 0; r < 4; r++) {
                    const int row = tile_m + wr * 64 + mi * 16 + kq * 4 + r;
                    const int col = tile_n + wc * 64 + ni * 16 + r16;
                    C[(long)row * N + col] = f2b(acc[mi][ni][r] * scale);
                }
    } else if (MODE == 1) {
        float* C = (float*)Cv;
        #pragma unroll
        for (int mi = 0; mi < 4; mi++)
            #pragma unroll
            for (int ni = 0; ni < 4; ni++)
                #pragma unroll
                for (int r = 0; r < 4; r++) {
                    const int row = tile_m + wr * 64 + mi * 16 + kq * 4 + r;
                    const int col = tile_n + wc * 64 + ni * 16 + r16;
                    C[(long)row * N + col] =
                        acc[mi][ni][r] + bias[col] + resid[(long)row * N + col];
                }
    } else if (MODE == 2) {
        // PV: normalize by rowsum
        ushort_t* C = (ushort_t*)Cv + (long)bz * batchC;
        const float* rs = rowsum + (long)bz * 2048;
        #pragma unroll
        for (int mi = 0; mi < 4; mi++) {
            float inv[4];
            #pragma unroll
            for (int r = 0; r < 4; r++)
                inv[r] = 1.0f / rs[tile_m + wr * 64 + mi * 16 + kq * 4 + r];
            #pragma unroll
            for (int ni = 0; ni < 4; ni++)
                #pragma unroll
                for (int r = 0; r < 4; r++) {
                    const int row = tile_m + wr * 64 + mi * 16 + kq * 4 + r;
                    const int col = tile_n + wc * 64 + ni * 16 + r16;
                    C[(long)row * N + col] = f2b(acc[mi][ni][r] * inv[r]);
                }
        }
    } else if (MODE == 3) {
        // scores: exp (no max-subtraction; |s|<~2 bounded) + atomic row sums
        ushort_t* C = (ushort_t*)Cv + (long)bz * batchC;
        float* rs = rowsum + (long)bz * 2048;
        #pragma unroll
        for (int mi = 0; mi < 4; mi++)
            #pragma unroll
            for (int r = 0; r < 4; r++) {
                const int row = tile_m + wr * 64 + mi * 16 + kq * 4 + r;
                float psum = 0.f;
                #pragma unroll
                for (int ni = 0; ni < 4; ni++) {
                    const float e = __expf(acc[mi][ni][r] * scale);
                    psum += e;
                    const int col = tile_n + wc * 64 + ni * 16 + r16;
                    C[(long)row * N + col] = f2b(e);
                }
                psum += __shfl_xor(psum, 1);
                psum += __shfl_xor(psum, 2);
                psum += __shfl_xor(psum, 4);
                psum += __shfl_xor(psum, 8);
                if (r16 == 0) atomicAdd(&rs[row], psum);
            }
    } else {
        // MODE 4: fused QKV. Cv = Qb base; sections of MROWS*768 each.
        const int sect  = tile_n / 768;          // 0=Q 1=K 2=V (128 | 768)
        const int ncol0 = tile_n - sect * 768;
        ushort_t* C = (ushort_t*)Cv + (size_t)sect * ((size_t)MROWS * 768);
        const float sc = (sect == 0) ? scale : 1.0f;
        #pragma unroll
        for (int mi = 0; mi < 4; mi++)
            #pragma unroll
            for (int ni = 0; ni < 4; ni++)
                #pragma unroll
                for (int r = 0; r < 4; r++) {
                    const int row = tile_m + wr * 64 + mi * 16 + kq * 4 + r;
                    const int col = ncol0 + wc * 64 + ni * 16 + r16;
                    C[(long)row * 768 + col] = f2b(acc[mi][ni][r] * sc);
                }
    }
}

// ---------------------------------------------------------------------------
// Fallback GEMM (round-3 proven) — only if ws too small for fast paths
// ---------------------------------------------------------------------------
template<int TRANSB, int MODE, int BF32>
__global__ __launch_bounds__(256)
void gemm_s(const ushort_t* __restrict__ A, const void* __restrict__ Bsrc,
            void* __restrict__ Cv, int M, int N, int Kd, float scale,
            const float* __restrict__ bias, const float* __restrict__ resid)
{
    __shared__ __align__(16) ushort_t As[128 * LDST];
    __shared__ __align__(16) ushort_t Bs[128 * LDST];
    const int tile_n = blockIdx.x * 128;
    const int tile_m = blockIdx.y * 128;
    const int tid  = threadIdx.x;
    const int w    = tid >> 6;
    const int lane = tid & 63;
    const int wr = w >> 1, wc = w & 1;
    const int r16 = lane & 15;
    const int kq  = lane >> 4;
    f32x4 acc[4][4] = {};
    for (int k0 = 0; k0 < Kd; k0 += 32) {
        #pragma unroll
        for (int cc = 0; cc < 2; cc++) {
            const int c = tid + cc * 256;
            const int row = c >> 2, col = (c & 3) * 8;
            *(uint4*)&As[row * LDST + col] = *(const uint4*)(A + (long)(tile_m + row) * Kd + k0 + col);
        }
        if (TRANSB == 0) {
            const ushort_t* Bt = (const ushort_t*)Bsrc;
            #pragma unroll
            for (int cc = 0; cc < 2; cc++) {
                const int c = tid + cc * 256;
                const int row = c >> 2, col = (c & 3) * 8;
                *(uint4*)&Bs[row * LDST + col] = *(const uint4*)(Bt + (long)(tile_n + row) * Kd + k0 + col);
            }
        } else {
            #pragma unroll
            for (int i = 0; i < 16; i++) {
                const int lin = i * 256 + tid;
                const int kr = lin >> 7, nc = lin & 127;
                ushort_t bv;
                if (BF32) bv = f2b(((const float*)Bsrc)[(long)(k0 + kr) * N + tile_n + nc]);
                else      bv = ((const ushort_t*)Bsrc)[(long)(k0 + kr) * N + tile_n + nc];
                Bs[nc * LDST + kr] = bv;
            }
        }
        __syncthreads();
        bf16x8 af[4], bg[4];
        #pragma unroll
        for (int i = 0; i < 4; i++) {
            af[i] = *reinterpret_cast<const bf16x8*>(&As[(wr * 64 + i * 16 + r16) * LDST + kq * 8]);
            bg[i] = *reinterpret_cast<const bf16x8*>(&Bs[(wc * 64 + i * 16 + r16) * LDST + kq * 8]);
        }
        #pragma unroll
        for (int mi = 0; mi < 4; mi++)
            #pragma unroll
            for (int ni = 0; ni < 4; ni++)
                acc[mi][ni] = __builtin_amdgcn_mfma_f32_16x16x32_bf16(af[mi], bg[ni], acc[mi][ni], 0, 0, 0);
        __syncthreads();
    }
    if (MODE == 0) {
        ushort_t* C = (ushort_t*)Cv;
        #pragma unroll
        for (int mi = 0; mi < 4; mi++)
            #pragma unroll
            for (int ni = 0; ni < 4; ni++)
                #pragma unroll
                for (int r = 0; r < 4; r++) {
                    const int row = tile_m + wr * 64 + mi * 16 + kq * 4 + r;
                    const int col = tile_n + wc * 64 + ni * 16 + r16;
                    C[(long)row * N + col] = f2b(acc[mi][ni][r] * scale);
                }
    } else {
        float* C = (float*)Cv;
        #pragma unroll
        for (int mi = 0; mi < 4; mi++)
            #pragma unroll
            for (int ni = 0; ni < 4; ni++)
                #pragma unroll
                for (int r = 0; r < 4; r++) {
                    const int row = tile_m + wr * 64 + mi * 16 + kq * 4 + r;
                    const int col = tile_n + wc * 64 + ni * 16 + r16;
                    C[(long)row * N + col] =
                        acc[mi][ni][r] + bias[col] + resid[(long)row * N + col];
                }
    }
}

// softmax over rows of 2048 bf16 (fallback path only)
__global__ void softmax_rows(ushort_t* __restrict__ p)
{
    __shared__ float sm[4], ss_[4];
    ushort_t* pr = p + (long)blockIdx.x * 2048;
    const int tid = threadIdx.x;
    const int w = tid >> 6;
    const uint4 raw = *(const uint4*)(pr + tid * 8);
    float v[8];
    v[0] = b2f((ushort_t)(raw.x & 0xffff)); v[1] = b2f((ushort_t)(raw.x >> 16));
    v[2] = b2f((ushort_t)(raw.y & 0xffff)); v[3] = b2f((ushort_t)(raw.y >> 16));
    v[4] = b2f((ushort_t)(raw.z & 0xffff)); v[5] = b2f((ushort_t)(raw.z >> 16));
    v[6] = b2f((ushort_t)(raw.w & 0xffff)); v[7] = b2f((ushort_t)(raw.w >> 16));
    float mx = -3.0e38f;
    #pragma unroll
    for (int i = 0; i < 8; i++) mx = fmaxf(mx, v[i]);
    #pragma unroll
    for (int off = 32; off; off >>= 1) mx = fmaxf(mx, __shfl_xor(mx, off));
    if ((tid & 63) == 0) sm[w] = mx;
    __syncthreads();
    mx = fmaxf(fmaxf(sm[0], sm[1]), fmaxf(sm[2], sm[3]));
    float s = 0.f;
    #pragma unroll
    for (int i = 0; i < 8; i++) { v[i] = __expf(v[i] - mx); s += v[i]; }
    #pragma unroll
    for (int off = 32; off; off >>= 1) s += __shfl_xor(s, off);
    if ((tid & 63) == 0) ss_[w] = s;
    __syncthreads();
    s = ss_[0] + ss_[1] + ss_[2] + ss_[3];
    const float inv = 1.f / s;
    uint4 o;
    o.x = f2b(v[0] * inv) | ((unsigned)f2b(v[1] * inv) << 16);
    o.y = f2b(v[2] * inv) | ((unsigned)f2b(v[3] * inv) << 16);
    o.z = f2b(v[4] * inv) | ((unsigned)f2b(v[5] * inv) << 16);
    o.w = f2b(v[6] * inv) | ((unsigned)f2b(v[7] * inv) << 16);
    *(uint4*)(pr + tid * 8) = o;
}

// double layernorm per fp32 row of 768, IN PLACE
__global__ void ln_fused(float* __restrict__ x,
                         const float* __restrict__ w1, const float* __restrict__ b1,
                         const float* __restrict__ w2, const float* __restrict__ b2)
{
    __shared__ float r1s[4], r1q[4], r2s[4], r2q[4];
    const long row = blockIdx.x;
    const int tid = threadIdx.x;
    const int w = tid >> 6;
    float* xr = x + row * 768;
    float v[3], s = 0.f, q = 0.f;
    #pragma unroll
    for (int i = 0; i < 3; i++) { const float t = xr[tid + i * 256]; v[i] = t; s += t; q += t * t; }
    #pragma unroll
    for (int off = 32; off; off >>= 1) { s += __shfl_xor(s, off); q += __shfl_xor(q, off); }
    if ((tid & 63) == 0) { r1s[w] = s; r1q[w] = q; }
    __syncthreads();
    s = r1s[0] + r1s[1] + r1s[2] + r1s[3];
    q = r1q[0] + r1q[1] + r1q[2] + r1q[3];
    float mu = s * (1.f / 768.f);
    float ri = rsqrtf(q * (1.f / 768.f) - mu * mu + EPS);
    float y[3];
    s = 0.f; q = 0.f;
    #pragma unroll
    for (int i = 0; i < 3; i++) {
        const int d = tid + i * 256;
        const float t = (v[i] - mu) * ri * w1[d] + b1[d];
        y[i] = t; s += t; q += t * t;
    }
    #pragma unroll
    for (int off = 32; off; off >>= 1) { s += __shfl_xor(s, off); q += __shfl_xor(q, off); }
    if ((tid & 63) == 0) { r2s[w] = s; r2q[w] = q; }
    __syncthreads();
    s = r2s[0] + r2s[1] + r2s[2] + r2s[3];
    q = r2q[0] + r2q[1] + r2q[2] + r2q[3];
    mu = s * (1.f / 768.f);
    ri = rsqrtf(q * (1.f / 768.f) - mu * mu + EPS);
    #pragma unroll
    for (int i = 0; i < 3; i++) {
        const int d = tid + i * 256;
        xr[d] = (y[i] - mu) * ri * w2[d] + b2[d];
    }
}

__global__ void pool_reduce(const float* __restrict__ x, float* __restrict__ pooled)
{
    const int d  = blockIdx.x * 256 + threadIdx.x;
    const int b  = blockIdx.z;
    const int sp = blockIdx.y;
    const float* base = x + ((long)b * 2048 + sp * 128) * 768 + d;
    float s = 0.f;
    #pragma unroll 8
    for (int i = 0; i < 128; i++) s += base[(long)i * 768];
    atomicAdd(&pooled[b * 768 + d], s);
}

// 80 blocks x 64 lanes: one wave per (b, o)
__global__ void logits_kernel(const float* __restrict__ pooled, const float* __restrict__ Wc,
                              const float* __restrict__ bc, float* __restrict__ out)
{
    const int b = blockIdx.x / 10, o = blockIdx.x % 10;
    const int lane = threadIdx.x;
    float s = 0.f;
    #pragma unroll
    for (int d = lane; d < 768; d += 64) s += pooled[b * 768 + d] * Wc[d * 10 + o];
    #pragma unroll
    for (int off = 32; off; off >>= 1) s += __shfl_xor(s, off);
    if (lane == 0) out[b * 10 + o] = s * (1.f / 2048.f) + bc[o];
}

extern "C" void kernel_launch(void* const* d_in, const int* in_sizes, int n_in,
                              void* d_out, int out_size, void* d_ws, size_t ws_size,
                              hipStream_t stream)
{
    (void)in_sizes; (void)n_in; (void)out_size;
    const float* src  = (const float*)d_in[0];
    const float* Wq   = (const float*)d_in[1];
    const float* Wk   = (const float*)d_in[2];
    const float* Wv   = (const float*)d_in[3];
    const float* Wo   = (const float*)d_in[4];
    const float* bo   = (const float*)d_in[5];
    const float* ln1w = (const float*)d_in[6];
    const float* ln1b = (const float*)d_in[7];
    const float* ln2w = (const float*)d_in[8];
    const float* ln2b = (const float*)d_in[9];
    const float* Wc   = (const float*)d_in[10];
    const float* bc   = (const float*)d_in[11];
    float* out = (float*)d_out;

    const dim3 blk(256);
    const float qscale = 1.0f / sqrtf(768.0f);
    const long bs = (long)2048 * 768;

    const size_t WT    = (size_t)768 * 768 * 2;          // 256-mult: Wt bufs contiguous
    const size_t BUF   = (size_t)MROWS * 768 * 2;        // 256-mult: Q/K/V contiguous
    const size_t POOLB = 24576;
    const size_t RSB   = (size_t)B_ * 2048 * 4;          // rowsum, 64 KB
    const size_t PROBS8 = (size_t)8 * 2048 * 2048 * 2;
    const size_t needB = 4 * WT + 5 * BUF + POOLB + RSB;  // ~130.7 MB
    const size_t needA = needB + PROBS8;                  // ~197.8 MB

    char* ws = (char*)d_ws;
    size_t off = 0;
    auto alloc = [&](size_t bytes) { void* p = ws + off; off += (bytes + 255) & ~(size_t)255; return p; };

    if (ws_size >= needB) {
        ushort_t* Wtq  = (ushort_t*)alloc(WT);   // Wtq/Wtk/Wtv contiguous => fused QKV B operand
        ushort_t* Wtk  = (ushort_t*)alloc(WT);
        ushort_t* Wtv  = (ushort_t*)alloc(WT);
        ushort_t* Wto  = (ushort_t*)alloc(WT);
        ushort_t* srcb = (ushort_t*)alloc(BUF);
        ushort_t* Qb   = (ushort_t*)alloc(BUF);  // Qb/Kb/Vb contiguous => MODE 4 sect routing
        ushort_t* Kb   = (ushort_t*)alloc(BUF);
        ushort_t* Vb   = (ushort_t*)alloc(BUF);
        ushort_t* Vt   = (ushort_t*)alloc(BUF);
        float*  pooled = (float*)  alloc(POOLB);
        float*  rowsum = (float*)  alloc(RSB);
        const bool batched = (ws_size >= needA);
        ushort_t* probs = batched ? (ushort_t*)alloc(PROBS8) : srcb;  // srcb dead after QKV
        ushort_t* attn  = Vb;                                         // Vb dead after transpose
        float*    xpre  = out + 80;

        cast_f32_bf16<<<MROWS * 768 / 1024, blk, 0, stream>>>(src, srcb, (long)MROWS * 768);
        transpose_any<1><<<dim3(12, 12, 1), blk, 0, stream>>>(Wq, Wtq, 768, 768, 0, 0);
        transpose_any<1><<<dim3(12, 12, 1), blk, 0, stream>>>(Wk, Wtk, 768, 768, 0, 0);
        transpose_any<1><<<dim3(12, 12, 1), blk, 0, stream>>>(Wv, Wtv, 768, 768, 0, 0);
        transpose_any<1><<<dim3(12, 12, 1), blk, 0, stream>>>(Wo, Wto, 768, 768, 0, 0);

        // fused QKV: [16384,768] @ [2304,768]^T, outputs routed per 768-col section
        gemm_nt<4><<<dim3(18, 128, 1), blk, 0, stream>>>(srcb, Wtq, Qb, MROWS, 2304, 768,
                                                         0, 0, 0, qscale, nullptr, nullptr, nullptr);

        transpose_any<0><<<dim3(12, 32, B_), blk, 0, stream>>>(Vb, Vt, 2048, 768, bs, bs);
        hipMemsetAsync(rowsum, 0, RSB, stream);

        if (batched) {
            // scores: exp(QK^T) with fused row-sum atomics
            gemm_nt<3><<<dim3(16, 16, B_), blk, 0, stream>>>(Qb, Kb, probs, 2048, 2048, 768,
                                                             bs, bs, (long)2048 * 2048, 1.0f,
                                                             nullptr, nullptr, rowsum);
            // PV: normalize by rowsum in epilogue
            gemm_nt<2><<<dim3(6, 16, B_), blk, 0, stream>>>(probs, Vt, attn, 2048, 768, 2048,
                                                            (long)2048 * 2048, bs, bs, 1.0f,
                                                            nullptr, nullptr, rowsum);
        } else {
            for (int bz = 0; bz < B_; bz += 2) {
                gemm_nt<3><<<dim3(16, 16, 2), blk, 0, stream>>>(Qb + bz * bs, Kb + bz * bs, probs,
                                                                2048, 2048, 768, bs, bs, (long)2048 * 2048,
                                                                1.0f, nullptr, nullptr, rowsum + bz * 2048);
                gemm_nt<2><<<dim3(6, 16, 2), blk, 0, stream>>>(probs, Vt + bz * bs, attn + bz * bs,
                                                               2048, 768, 2048,
                                                               (long)2048 * 2048, bs, bs, 1.0f,
                                                               nullptr, nullptr, rowsum + bz * 2048);
            }
        }

        gemm_nt<1><<<dim3(6, 128, 1), blk, 0, stream>>>(attn, Wto, xpre, MROWS, 768, 768,
                                                        0, 0, 0, 1.0f, bo, src, nullptr);
        ln_fused<<<MROWS, blk, 0, stream>>>(xpre, ln1w, ln1b, ln2w, ln2b);
        hipMemsetAsync(pooled, 0, B_ * 768 * 4, stream);
        pool_reduce<<<dim3(3, 16, B_), blk, 0, stream>>>(xpre, pooled);
        logits_kernel<<<80, 64, 0, stream>>>(pooled, Wc, bc, out);
    } else {
        // round-3 proven fallback (~100.7 MB)
        ushort_t* srcb = (ushort_t*)alloc(BUF);
        ushort_t* Qb   = (ushort_t*)alloc(BUF);
        ushort_t* Kb   = (ushort_t*)alloc(BUF);
        ushort_t* Vb   = (ushort_t*)alloc(BUF);
        float*  pooled = (float*)  alloc(POOLB);
        ushort_t* probs = srcb;
        ushort_t* attn  = Qb;
        float*    xpre  = out + 80;

        cast_f32_bf16<<<MROWS * 768 / 1024, blk, 0, stream>>>(src, srcb, (long)MROWS * 768);
        gemm_s<1, 0, 1><<<dim3(6, 128), blk, 0, stream>>>(srcb, Wq, Qb, MROWS, 768, 768, qscale, nullptr, nullptr);
        gemm_s<1, 0, 1><<<dim3(6, 128), blk, 0, stream>>>(srcb, Wk, Kb, MROWS, 768, 768, 1.0f, nullptr, nullptr);
        gemm_s<1, 0, 1><<<dim3(6, 128), blk, 0, stream>>>(srcb, Wv, Vb, MROWS, 768, 768, 1.0f, nullptr, nullptr);
        for (int bz = 0; bz < B_; bz++) {
            gemm_s<0, 0, 0><<<dim3(16, 16), blk, 0, stream>>>(Qb + bz * bs, Kb + bz * bs, probs,
                                                              2048, 2048, 768, 1.0f, nullptr, nullptr);
            softmax_rows<<<2048, blk, 0, stream>>>(probs);
            gemm_s<1, 0, 0><<<dim3(6, 16), blk, 0, stream>>>(probs, Vb + bz * bs, attn + bz * bs,
                                                             2048, 768, 2048, 1.0f, nullptr, nullptr);
        }
        gemm_s<1, 1, 1><<<dim3(6, 128), blk, 0, stream>>>(attn, Wo, xpre, MROWS, 768, 768, 1.0f, bo, src);
        ln_fused<<<MROWS, blk, 0, stream>>>(xpre, ln1w, ln1b, ln2w, ln2b);
        hipMemsetAsync(pooled, 0, B_ * 768 * 4, stream);
        pool_reduce<<<dim3(3, 16, B_), blk, 0, stream>>>(xpre, pooled);
        logits_kernel<<<80, 64, 0, stream>>>(pooled, Wc, bc, out);
    }
}